// Round 5
// baseline (316.354 us; speedup 1.0000x reference)
//
#include <hip/hip_runtime.h>
#include <hip/hip_bf16.h>

typedef __attribute__((ext_vector_type(8))) short bf16x8;
typedef __attribute__((ext_vector_type(4))) float f32x4;
typedef unsigned short u16;
typedef unsigned int u32;

#define LHS_STRIDE 8421376   // 16*514*1024 floats per stack slot
#define RHS_STRIDE 524288    // 512*1024 floats per stack slot
#define TBL_SPLIT  8224      // 16*514
#define AN 257               // sequence length
#define NR 4112              // 16*257 total rows
#define KSD 72               // K LDS row stride: 144B (16B-mult, bank stride 4 -> 2-way free)
#define VSD 260              // V^T LDS row stride: 520B (bank stride 2 -> conflict-free reads)

// row pointer into the concatenated [lhs | rhs] table for stack slot s
__device__ __forceinline__ const float* tbl_row(int s, int g,
    const float* __restrict__ lhs, const float* __restrict__ rhs) {
  if (g < TBL_SPLIT) return lhs + (size_t)s * LHS_STRIDE + (size_t)g * 1024;
  return rhs + (size_t)s * RHS_STRIDE + (size_t)(g - TBL_SPLIT) * 1024;
}

__device__ __forceinline__ u16 f2b(float x) {
  union { __hip_bfloat16 b; u16 u; } c;
  c.b = __float2bfloat16(x);
  return c.u;
}

__device__ __forceinline__ u32 pk2(float a, float b) {
  return (u32)f2b(a) | ((u32)f2b(b) << 16);
}

__device__ __forceinline__ bf16x8 mk8(ushort4 a, ushort4 b) {
  bf16x8 r;
  r[0] = (short)a.x; r[1] = (short)a.y; r[2] = (short)a.z; r[3] = (short)a.w;
  r[4] = (short)b.x; r[5] = (short)b.y; r[6] = (short)b.z; r[7] = (short)b.w;
  return r;
}

// async global->LDS, 16B per lane; LDS dest = wave-uniform base + lane*16
__device__ __forceinline__ void gload16(const u16* g, u16* l) {
  __builtin_amdgcn_global_load_lds((const __attribute__((address_space(1))) void*)g,
                                   (__attribute__((address_space(3))) void*)l,
                                   16, 0, 0);
}

// ---------------------------------------------------------------------------
// gather_cvt: blocks 0..4111 -> q (scaled 1/8), 4112..8223 -> k, 8224..12335 -> v,
// 12336..13359 -> Wo rows. One 4KB row per block, coalesced, f32 -> bf16.
__global__ void gather_cvt_kernel(
    const int* __restrict__ gidx, const float* __restrict__ lhs,
    const float* __restrict__ rhs, const float* __restrict__ Wo,
    u16* __restrict__ q_bf, u16* __restrict__ k_bf, u16* __restrict__ v_bf,
    u16* __restrict__ wo_bf) {
  const int blk = blockIdx.x, t = threadIdx.x;
  const float* src;
  u16* dst;
  float sc = 1.0f;
  if (blk < 3 * NR) {
    const int s = blk / NR + 1;            // 1=q, 2=k, 3=v
    const int row = blk - (s - 1) * NR;
    src = tbl_row(s, gidx[row], lhs, rhs);
    if (s == 1) { sc = 0.125f; dst = q_bf + (size_t)row * 1024; }
    else if (s == 2) dst = k_bf + (size_t)row * 1024;
    else dst = v_bf + (size_t)row * 1024;
  } else {
    const int row = blk - 3 * NR;          // 0..1023
    src = Wo + (size_t)row * 1024;
    dst = wo_bf + (size_t)row * 1024;
  }
  float4 v = *(const float4*)(src + t * 4);
  *(ushort4*)(dst + t * 4) =
      make_ushort4(f2b(sc * v.x), f2b(sc * v.y), f2b(sc * v.z), f2b(sc * v.w));
}

// ---------------------------------------------------------------------------
// attn: one block per (b,h), 8 waves, all inputs already bf16 + q pre-scaled.
// Swapped QK^T (S^T = mfma(K,Q), scores lane-local), in-register softmax,
// PV A-fragments rebuilt via shfl. One barrier total. No launch-bounds VGPR cap.
struct __align__(16) AttnSmem {
  u16 K[272 * KSD];   // 39168 B; rows 257..271 stale (scores masked post-MFMA)
  u16 VT[64 * VSD];   // 33280 B; keys 0..256 written, 257..259 never read
};                    // 72448 B

__global__ __launch_bounds__(512) void attn_kernel(
    const u16* __restrict__ q_bf, const u16* __restrict__ k_bf,
    const u16* __restrict__ v_bf, u16* __restrict__ attn_out) {
  __shared__ AttnSmem sm;
  const int bh = blockIdx.x, b = bh >> 4, h = bh & 15;
  const int t = threadIdx.x, wave = t >> 6, lane = t & 63;
  const int lg = lane >> 4, lr = lane & 15;
  const u16* qb = q_bf + (size_t)b * AN * 1024 + h * 64;
  const u16* kb = k_bf + (size_t)b * AN * 1024 + h * 64;
  const u16* vb = v_bf + (size_t)b * AN * 1024 + h * 64;

  // ---- stage K row-major (16B chunks) and V^T (reg transpose, scalar writes)
  {
    const int r8 = t >> 3, c8 = (t & 7) * 8;
#pragma unroll
    for (int p = 0; p < 5; ++p) {
      int r = p * 64 + r8;
      if (r < AN) {
        uint4 kx = *(const uint4*)(kb + (size_t)r * 1024 + c8);
        *(uint4*)&sm.K[r * KSD + c8] = kx;
        ushort4 v0 = *(const ushort4*)(vb + (size_t)r * 1024 + c8);
        ushort4 v1 = *(const ushort4*)(vb + (size_t)r * 1024 + c8 + 4);
        sm.VT[(c8 + 0) * VSD + r] = v0.x; sm.VT[(c8 + 1) * VSD + r] = v0.y;
        sm.VT[(c8 + 2) * VSD + r] = v0.z; sm.VT[(c8 + 3) * VSD + r] = v0.w;
        sm.VT[(c8 + 4) * VSD + r] = v1.x; sm.VT[(c8 + 5) * VSD + r] = v1.y;
        sm.VT[(c8 + 6) * VSD + r] = v1.z; sm.VT[(c8 + 7) * VSD + r] = v1.w;
      }
    }
  }

  // ---- Q fragments for owned row-tiles: direct 16B bf16 loads (pre-scaled)
  const int ntile = (wave == 0) ? 3 : 2;
  const int rts[3] = {wave, wave + 8, 16};
  bf16x8 qa[3][2];
#pragma unroll
  for (int ti = 0; ti < 3; ++ti) {
    if (ti < ntile) {
      int qrow = rts[ti] * 16 + lr; if (qrow > 256) qrow = 256;
      const u16* qp = qb + (size_t)qrow * 1024 + lg * 8;
      qa[ti][0] = *(const bf16x8*)qp;
      qa[ti][1] = *(const bf16x8*)(qp + 32);
    }
  }
  __syncthreads();   // the only barrier

  const int srcE = lr + ((lane & 16) << 1);  // lr + 32*(lg&1)
  const int srcO = srcE + 16;
  const bool useE = (lg < 2);

  for (int ti = 0; ti < ntile; ++ti) {
    const int r0 = rts[ti] * 16;

    // ---- QK^T swapped: lane holds S[q=lr][k=nf*16+lg*4+reg]
    f32x4 s[17];
#pragma unroll
    for (int nf = 0; nf < 17; ++nf) {
      const u16* kp = &sm.K[(nf * 16 + lr) * KSD + lg * 8];
      ushort4 x0 = *(const ushort4*)kp;
      ushort4 x1 = *(const ushort4*)(kp + 4);
      ushort4 y0 = *(const ushort4*)(kp + 32);
      ushort4 y1 = *(const ushort4*)(kp + 36);
      f32x4 acc = {0.f, 0.f, 0.f, 0.f};
      acc = __builtin_amdgcn_mfma_f32_16x16x32_bf16(mk8(x0, x1), qa[ti][0], acc, 0, 0, 0);
      acc = __builtin_amdgcn_mfma_f32_16x16x32_bf16(mk8(y0, y1), qa[ti][1], acc, 0, 0, 0);
      s[nf] = acc;
    }
    // mask keys >= 257 (nf=16 holds keys 256+lg*4+reg; only (lg=0,reg=0) real)
    s[16][1] = -1e30f; s[16][2] = -1e30f; s[16][3] = -1e30f;
    if (lg != 0) s[16][0] = -1e30f;

    // ---- softmax: in-lane over 68 values + reduce across 4 lanes sharing lr
    float m = -1e30f;
#pragma unroll
    for (int nf = 0; nf < 17; ++nf)
      m = fmaxf(m, fmaxf(fmaxf(s[nf][0], s[nf][1]), fmaxf(s[nf][2], s[nf][3])));
    m = fmaxf(m, __shfl_xor(m, 16));
    m = fmaxf(m, __shfl_xor(m, 32));
    float sum = 0.f;
#pragma unroll
    for (int nf = 0; nf < 17; ++nf) {
#pragma unroll
      for (int r = 0; r < 4; ++r) {
        float w = __expf(s[nf][r] - m);
        s[nf][r] = w;
        sum += w;
      }
    }
    sum += __shfl_xor(sum, 16);
    sum += __shfl_xor(sum, 32);
    const float inv = 1.0f / sum;

    // ---- P x V with in-register P redistribution (no LDS round-trip)
    f32x4 zero = {0.f, 0.f, 0.f, 0.f};
    f32x4 o[4] = {zero, zero, zero, zero};
#pragma unroll
    for (int ks = 0; ks < 8; ++ks) {
      u32 e0 = pk2(s[2 * ks][0] * inv, s[2 * ks][1] * inv);
      u32 e1 = pk2(s[2 * ks][2] * inv, s[2 * ks][3] * inv);
      u32 f0 = pk2(s[2 * ks + 1][0] * inv, s[2 * ks + 1][1] * inv);
      u32 f1 = pk2(s[2 * ks + 1][2] * inv, s[2 * ks + 1][3] * inv);
      u32 A0 = (u32)__shfl((int)e0, srcE), A1 = (u32)__shfl((int)e1, srcE);
      u32 A2 = (u32)__shfl((int)e0, srcO), A3 = (u32)__shfl((int)e1, srcO);
      u32 B0 = (u32)__shfl((int)f0, srcE), B1 = (u32)__shfl((int)f1, srcE);
      u32 B2 = (u32)__shfl((int)f0, srcO), B3 = (u32)__shfl((int)f1, srcO);
      union { u32 w[4]; bf16x8 v; } pa;
      pa.w[0] = useE ? A0 : B0; pa.w[1] = useE ? A1 : B1;
      pa.w[2] = useE ? A2 : B2; pa.w[3] = useE ? A3 : B3;
#pragma unroll
      for (int nd = 0; nd < 4; ++nd) {
        const u16* vp = &sm.VT[(nd * 16 + lr) * VSD + ks * 32 + lg * 8];
        bf16x8 vbr = mk8(*(const ushort4*)vp, *(const ushort4*)(vp + 4));
        o[nd] = __builtin_amdgcn_mfma_f32_16x16x32_bf16(pa.v, vbr, o[nd], 0, 0, 0);
      }
    }
    {  // ks=8: only key 256 real; masked exps are exactly 0 so pa needs no guard
      union { u32 w[4]; bf16x8 v; } pa;
      pa.w[0] = pk2(s[16][0] * inv, 0.f);
      pa.w[1] = 0; pa.w[2] = 0; pa.w[3] = 0;
#pragma unroll
      for (int nd = 0; nd < 4; ++nd) {
        union { u32 w[4]; bf16x8 v; } vv;
        vv.w[0] = (lg == 0) ? (u32)sm.VT[(nd * 16 + lr) * VSD + 256] : 0u;
        vv.w[1] = 0; vv.w[2] = 0; vv.w[3] = 0;
        o[nd] = __builtin_amdgcn_mfma_f32_16x16x32_bf16(pa.v, vv.v, o[nd], 0, 0, 0);
      }
    }

    // ---- store: row = q = lg*4+reg, col = d = nd*16+lr
#pragma unroll
    for (int nd = 0; nd < 4; ++nd)
#pragma unroll
      for (int reg = 0; reg < 4; ++reg) {
        int row = r0 + lg * 4 + reg;
        if (row < AN)
          attn_out[(size_t)(b * AN + row) * 1024 + h * 64 + nd * 16 + lr] =
              f2b(o[nd][reg]);
      }
  }
}

// ---------------------------------------------------------------------------
// out[4112][1024] = attn(bf16) x Wo(bf16)^T + bo + hidden(gathered), f32 out.
// Double-buffered global_load_lds + XCD-aware block swizzle (264 = 8 XCD x 33).
__global__ __launch_bounds__(256, 1) void gemm_kernel(
    const u16* __restrict__ A, const u16* __restrict__ Bw,
    const float* __restrict__ bo, const int* __restrict__ gidx,
    const float* __restrict__ lhs, const float* __restrict__ rhs,
    float* __restrict__ out) {
  __shared__ __align__(16) u16 As[2][128 * 32];
  __shared__ __align__(16) u16 Bs[2][128 * 32];
  const int t = threadIdx.x, wave = t >> 6, lane = t & 63;
  const int lg = lane >> 4, lr = lane & 15;
  // XCD swizzle: blocks on the same XCD (bid%8) share consecutive mt -> A-tile L2 reuse
  const int linear = (blockIdx.x & 7) * 33 + (blockIdx.x >> 3);
  const int mt = linear >> 3, nt = linear & 7;
  const int m0 = mt * 128, n0 = nt * 128;
  const int wm = wave >> 1, wn = wave & 1;

  f32x4 zero = {0.f, 0.f, 0.f, 0.f};
  f32x4 acc[4][4];
#pragma unroll
  for (int i = 0; i < 4; ++i)
#pragma unroll
    for (int j = 0; j < 4; ++j) acc[i][j] = zero;

  const int srow = lane >> 2;
  const int scol = (((lane & 3) ^ ((lane >> 3) & 3))) * 8;  // pre-swizzled col-group
  const int ss = (lg ^ ((lr >> 1) & 3)) * 8;                // swizzled read slot

#define STAGE(buf, kt)                                                          \
  {                                                                             \
    const int k0 = (kt) * 32;                                                   \
    _Pragma("unroll")                                                           \
    for (int i = 0; i < 2; ++i) {                                               \
      int row = wave * 32 + i * 16 + srow;                                      \
      int arow = m0 + row; if (arow > 4111) arow = 4111;                        \
      gload16(A + (size_t)arow * 1024 + k0 + scol, &As[buf][wave * 1024 + i * 512]); \
      gload16(Bw + (size_t)(n0 + row) * 1024 + k0 + scol, &Bs[buf][wave * 1024 + i * 512]); \
    }                                                                           \
  }

  STAGE(0, 0)
  __syncthreads();
  int cur = 0;
  for (int kt = 0; kt < 32; ++kt) {
    if (kt < 31) STAGE(cur ^ 1, kt + 1)   // prefetch overlaps this tile's compute
    bf16x8 af[4], bfr[4];
#pragma unroll
    for (int i = 0; i < 4; ++i) {
      af[i]  = *(const bf16x8*)&As[cur][(wm * 64 + i * 16 + lr) * 32 + ss];
      bfr[i] = *(const bf16x8*)&Bs[cur][(wn * 64 + i * 16 + lr) * 32 + ss];
    }
#pragma unroll
    for (int i = 0; i < 4; ++i)
#pragma unroll
      for (int j = 0; j < 4; ++j)
        acc[i][j] = __builtin_amdgcn_mfma_f32_16x16x32_bf16(af[i], bfr[j], acc[i][j], 0, 0, 0);
    __syncthreads();
    cur ^= 1;
  }
#undef STAGE

  // epilogue: residual (gathered hidden) + bias
#pragma unroll
  for (int i = 0; i < 4; ++i)
#pragma unroll
    for (int j = 0; j < 4; ++j)
#pragma unroll
      for (int reg = 0; reg < 4; ++reg) {
        int row = m0 + wm * 64 + i * 16 + lg * 4 + reg;
        int col = n0 + wn * 64 + j * 16 + lr;
        if (row < 4112) {
          int g = gidx[row];
          out[(size_t)row * 1024 + col] =
              tbl_row(0, g, lhs, rhs)[col] + bo[col] + acc[i][j][reg];
        }
      }
}

extern "C" void kernel_launch(void* const* d_in, const int* in_sizes, int n_in,
                              void* d_out, int out_size, void* d_ws, size_t ws_size,
                              hipStream_t stream) {
  const int*   gidx = (const int*)d_in[0];
  const float* lhs  = (const float*)d_in[1];
  const float* rhs  = (const float*)d_in[2];
  const float* Wo   = (const float*)d_in[3];
  const float* bo   = (const float*)d_in[4];
  float* out = (float*)d_out;

  u16* q_bf    = (u16*)d_ws;                      // 4112*1024 bf16 = 8.42 MB each
  u16* k_bf    = q_bf + (size_t)NR * 1024;
  u16* v_bf    = k_bf + (size_t)NR * 1024;
  u16* attn_ws = v_bf + (size_t)NR * 1024;
  u16* wo_bf   = attn_ws + (size_t)NR * 1024;     // 1024*1024 bf16 = 2.10 MB

  gather_cvt_kernel<<<3 * NR + 1024, 256, 0, stream>>>(gidx, lhs, rhs, Wo,
                                                       q_bf, k_bf, v_bf, wo_bf);
  attn_kernel<<<256, 512, 0, stream>>>(q_bf, k_bf, v_bf, attn_ws);
  gemm_kernel<<<264, 256, 0, stream>>>(attn_ws, wo_bf, bo, gidx, lhs, rhs, out);
}

// Round 6
// 291.104 us; speedup vs baseline: 1.0867x; 1.0867x over previous
//
#include <hip/hip_runtime.h>
#include <hip/hip_bf16.h>

typedef __attribute__((ext_vector_type(8))) short bf16x8;
typedef __attribute__((ext_vector_type(4))) float f32x4;
typedef unsigned short u16;
typedef unsigned int u32;

#define LHS_STRIDE 8421376   // 16*514*1024 floats per stack slot
#define RHS_STRIDE 524288    // 512*1024 floats per stack slot
#define TBL_SPLIT  8224      // 16*514
#define AN 257               // sequence length
#define NR 4112              // 16*257 total rows
#define KSD 72               // K LDS row stride: 144B (16B-mult, bank stride 4 -> 2-way free)
#define VSD 260              // V^T LDS row stride: 520B (bank stride 2 -> conflict-free reads)

// row pointer into the concatenated [lhs | rhs] table for stack slot s
__device__ __forceinline__ const float* tbl_row(int s, int g,
    const float* __restrict__ lhs, const float* __restrict__ rhs) {
  if (g < TBL_SPLIT) return lhs + (size_t)s * LHS_STRIDE + (size_t)g * 1024;
  return rhs + (size_t)s * RHS_STRIDE + (size_t)(g - TBL_SPLIT) * 1024;
}

__device__ __forceinline__ u16 f2b(float x) {
  union { __hip_bfloat16 b; u16 u; } c;
  c.b = __float2bfloat16(x);
  return c.u;
}

__device__ __forceinline__ u32 pk2(float a, float b) {
  return (u32)f2b(a) | ((u32)f2b(b) << 16);
}

__device__ __forceinline__ bf16x8 mk8(ushort4 a, ushort4 b) {
  bf16x8 r;
  r[0] = (short)a.x; r[1] = (short)a.y; r[2] = (short)a.z; r[3] = (short)a.w;
  r[4] = (short)b.x; r[5] = (short)b.y; r[6] = (short)b.z; r[7] = (short)b.w;
  return r;
}

// async global->LDS, 16B per lane; LDS dest = wave-uniform base + lane*16
__device__ __forceinline__ void gload16(const u16* g, u16* l) {
  __builtin_amdgcn_global_load_lds((const __attribute__((address_space(1))) void*)g,
                                   (__attribute__((address_space(3))) void*)l,
                                   16, 0, 0);
}

// ---------------------------------------------------------------------------
// gather_cvt: blocks 0..4111 -> q (scaled 1/8), 4112..8223 -> k, 8224..12335 -> v,
// 12336..13359 -> Wo rows. One 4KB row per block, coalesced, f32 -> bf16.
__global__ void gather_cvt_kernel(
    const int* __restrict__ gidx, const float* __restrict__ lhs,
    const float* __restrict__ rhs, const float* __restrict__ Wo,
    u16* __restrict__ q_bf, u16* __restrict__ k_bf, u16* __restrict__ v_bf,
    u16* __restrict__ wo_bf) {
  const int blk = blockIdx.x, t = threadIdx.x;
  const float* src;
  u16* dst;
  float sc = 1.0f;
  if (blk < 3 * NR) {
    const int s = blk / NR + 1;            // 1=q, 2=k, 3=v
    const int row = blk - (s - 1) * NR;
    src = tbl_row(s, gidx[row], lhs, rhs);
    if (s == 1) { sc = 0.125f; dst = q_bf + (size_t)row * 1024; }
    else if (s == 2) dst = k_bf + (size_t)row * 1024;
    else dst = v_bf + (size_t)row * 1024;
  } else {
    const int row = blk - 3 * NR;          // 0..1023
    src = Wo + (size_t)row * 1024;
    dst = wo_bf + (size_t)row * 1024;
  }
  float4 v = *(const float4*)(src + t * 4);
  *(ushort4*)(dst + t * 4) =
      make_ushort4(f2b(sc * v.x), f2b(sc * v.y), f2b(sc * v.z), f2b(sc * v.w));
}

// ---------------------------------------------------------------------------
// attn: one block per (b,h,half), 8 waves; half 0 owns q-tiles {wave, 16},
// half 1 owns {wave+8}. Swapped QK^T (scores lane-local), in-register softmax,
// PV A-fragments rebuilt via shfl. 2 blocks/CU -> 4 waves/SIMD.
struct __align__(16) AttnSmem {
  u16 K[272 * KSD];   // 39168 B; rows 257..271 stale (scores masked post-MFMA)
  u16 VT[64 * VSD];   // 33280 B; keys 0..256 written, 257..259 never read
};                    // 72448 B -> exactly 2 blocks/CU

__global__ __launch_bounds__(512) void attn_kernel(
    const u16* __restrict__ q_bf, const u16* __restrict__ k_bf,
    const u16* __restrict__ v_bf, u16* __restrict__ attn_out) {
  __shared__ AttnSmem sm;
  const int bh = blockIdx.x >> 1, half = blockIdx.x & 1;
  const int b = bh >> 4, h = bh & 15;
  const int t = threadIdx.x, wave = t >> 6, lane = t & 63;
  const int lg = lane >> 4, lr = lane & 15;
  const u16* qb = q_bf + (size_t)b * AN * 1024 + h * 64;
  const u16* kb = k_bf + (size_t)b * AN * 1024 + h * 64;
  const u16* vb = v_bf + (size_t)b * AN * 1024 + h * 64;

  // ---- stage K row-major (16B chunks) and V^T (reg transpose, scalar writes)
  {
    const int r8 = t >> 3, c8 = (t & 7) * 8;
#pragma unroll
    for (int p = 0; p < 5; ++p) {
      int r = p * 64 + r8;
      if (r < AN) {
        uint4 kx = *(const uint4*)(kb + (size_t)r * 1024 + c8);
        *(uint4*)&sm.K[r * KSD + c8] = kx;
        ushort4 v0 = *(const ushort4*)(vb + (size_t)r * 1024 + c8);
        ushort4 v1 = *(const ushort4*)(vb + (size_t)r * 1024 + c8 + 4);
        sm.VT[(c8 + 0) * VSD + r] = v0.x; sm.VT[(c8 + 1) * VSD + r] = v0.y;
        sm.VT[(c8 + 2) * VSD + r] = v0.z; sm.VT[(c8 + 3) * VSD + r] = v0.w;
        sm.VT[(c8 + 4) * VSD + r] = v1.x; sm.VT[(c8 + 5) * VSD + r] = v1.y;
        sm.VT[(c8 + 6) * VSD + r] = v1.z; sm.VT[(c8 + 7) * VSD + r] = v1.w;
      }
    }
  }

  // ---- Q fragments for owned row-tiles: direct 16B bf16 loads (pre-scaled)
  int rts[2];
  int ntile;
  if (half == 0) { rts[0] = wave; rts[1] = 16; ntile = (wave == 0) ? 2 : 1; }
  else           { rts[0] = wave + 8; rts[1] = 0; ntile = 1; }
  bf16x8 qa[2][2];
#pragma unroll
  for (int ti = 0; ti < 2; ++ti) {
    if (ti < ntile) {
      int qrow = rts[ti] * 16 + lr; if (qrow > 256) qrow = 256;
      const u16* qp = qb + (size_t)qrow * 1024 + lg * 8;
      qa[ti][0] = *(const bf16x8*)qp;
      qa[ti][1] = *(const bf16x8*)(qp + 32);
    }
  }
  __syncthreads();   // the only barrier

  const int srcE = lr + ((lane & 16) << 1);  // lr + 32*(lg&1)
  const int srcO = srcE + 16;
  const bool useE = (lg < 2);

  for (int ti = 0; ti < ntile; ++ti) {
    const int r0 = rts[ti] * 16;

    // ---- QK^T swapped: lane holds S[q=lr][k=nf*16+lg*4+reg]
    f32x4 s[17];
#pragma unroll
    for (int nf = 0; nf < 17; ++nf) {
      const u16* kp = &sm.K[(nf * 16 + lr) * KSD + lg * 8];
      ushort4 x0 = *(const ushort4*)kp;
      ushort4 x1 = *(const ushort4*)(kp + 4);
      ushort4 y0 = *(const ushort4*)(kp + 32);
      ushort4 y1 = *(const ushort4*)(kp + 36);
      f32x4 acc = {0.f, 0.f, 0.f, 0.f};
      acc = __builtin_amdgcn_mfma_f32_16x16x32_bf16(mk8(x0, x1), qa[ti][0], acc, 0, 0, 0);
      acc = __builtin_amdgcn_mfma_f32_16x16x32_bf16(mk8(y0, y1), qa[ti][1], acc, 0, 0, 0);
      s[nf] = acc;
    }
    // mask keys >= 257 (nf=16 holds keys 256+lg*4+reg; only (lg=0,reg=0) real)
    s[16][1] = -1e30f; s[16][2] = -1e30f; s[16][3] = -1e30f;
    if (lg != 0) s[16][0] = -1e30f;

    // ---- softmax: in-lane over 68 values + reduce across 4 lanes sharing lr
    float m = -1e30f;
#pragma unroll
    for (int nf = 0; nf < 17; ++nf)
      m = fmaxf(m, fmaxf(fmaxf(s[nf][0], s[nf][1]), fmaxf(s[nf][2], s[nf][3])));
    m = fmaxf(m, __shfl_xor(m, 16));
    m = fmaxf(m, __shfl_xor(m, 32));
    float sum = 0.f;
#pragma unroll
    for (int nf = 0; nf < 17; ++nf) {
#pragma unroll
      for (int r = 0; r < 4; ++r) {
        float w = __expf(s[nf][r] - m);
        s[nf][r] = w;
        sum += w;
      }
    }
    sum += __shfl_xor(sum, 16);
    sum += __shfl_xor(sum, 32);
    const float inv = 1.0f / sum;

    // ---- P x V with in-register P redistribution (no LDS round-trip)
    f32x4 zero = {0.f, 0.f, 0.f, 0.f};
    f32x4 o[4] = {zero, zero, zero, zero};
#pragma unroll
    for (int ks = 0; ks < 8; ++ks) {
      u32 e0 = pk2(s[2 * ks][0] * inv, s[2 * ks][1] * inv);
      u32 e1 = pk2(s[2 * ks][2] * inv, s[2 * ks][3] * inv);
      u32 f0 = pk2(s[2 * ks + 1][0] * inv, s[2 * ks + 1][1] * inv);
      u32 f1 = pk2(s[2 * ks + 1][2] * inv, s[2 * ks + 1][3] * inv);
      u32 A0 = (u32)__shfl((int)e0, srcE), A1 = (u32)__shfl((int)e1, srcE);
      u32 A2 = (u32)__shfl((int)e0, srcO), A3 = (u32)__shfl((int)e1, srcO);
      u32 B0 = (u32)__shfl((int)f0, srcE), B1 = (u32)__shfl((int)f1, srcE);
      u32 B2 = (u32)__shfl((int)f0, srcO), B3 = (u32)__shfl((int)f1, srcO);
      union { u32 w[4]; bf16x8 v; } pa;
      pa.w[0] = useE ? A0 : B0; pa.w[1] = useE ? A1 : B1;
      pa.w[2] = useE ? A2 : B2; pa.w[3] = useE ? A3 : B3;
#pragma unroll
      for (int nd = 0; nd < 4; ++nd) {
        const u16* vp = &sm.VT[(nd * 16 + lr) * VSD + ks * 32 + lg * 8];
        bf16x8 vbr = mk8(*(const ushort4*)vp, *(const ushort4*)(vp + 4));
        o[nd] = __builtin_amdgcn_mfma_f32_16x16x32_bf16(pa.v, vbr, o[nd], 0, 0, 0);
      }
    }
    {  // ks=8: only key 256 real; masked exps are exactly 0 so pa needs no guard
      union { u32 w[4]; bf16x8 v; } pa;
      pa.w[0] = pk2(s[16][0] * inv, 0.f);
      pa.w[1] = 0; pa.w[2] = 0; pa.w[3] = 0;
#pragma unroll
      for (int nd = 0; nd < 4; ++nd) {
        union { u32 w[4]; bf16x8 v; } vv;
        vv.w[0] = (lg == 0) ? (u32)sm.VT[(nd * 16 + lr) * VSD + 256] : 0u;
        vv.w[1] = 0; vv.w[2] = 0; vv.w[3] = 0;
        o[nd] = __builtin_amdgcn_mfma_f32_16x16x32_bf16(pa.v, vv.v, o[nd], 0, 0, 0);
      }
    }

    // ---- store: row = q = lg*4+reg, col = d = nd*16+lr
#pragma unroll
    for (int nd = 0; nd < 4; ++nd)
#pragma unroll
      for (int reg = 0; reg < 4; ++reg) {
        int row = r0 + lg * 4 + reg;
        if (row < AN)
          attn_out[(size_t)(b * AN + row) * 1024 + h * 64 + nd * 16 + lr] =
              f2b(o[nd][reg]);
      }
  }
}

// ---------------------------------------------------------------------------
// out[4112][1024] = attn(bf16) x Wo(bf16)^T + bo + hidden(gathered), f32 out.
// 64x64x64 tiles, single-buffered gload_lds, 1040 blocks (~4/CU -> 4 waves/SIMD).
// Row layout: 8 x 16B slots; slot stored/read XOR (row&7) -> conflict-free b128.
__global__ __launch_bounds__(256) void gemm_kernel(
    const u16* __restrict__ A, const u16* __restrict__ Bw,
    const float* __restrict__ bo, const int* __restrict__ gidx,
    const float* __restrict__ lhs, const float* __restrict__ rhs,
    float* __restrict__ out) {
  __shared__ __align__(16) u16 As[64 * 64];
  __shared__ __align__(16) u16 Bs[64 * 64];
  const int t = threadIdx.x, wave = t >> 6, lane = t & 63;
  const int lg = lane >> 4, lr = lane & 15;
  // XCD swizzle: 1040 = 8 x 130; same-XCD blocks get consecutive linear ids
  const int linear = (blockIdx.x & 7) * 130 + (blockIdx.x >> 3);
  const int mt = linear >> 4, nt = linear & 15;     // 65 x 16 tiles
  const int m0 = mt * 64, n0 = nt * 64;
  const int wm = wave >> 1, wn = wave & 1;

  f32x4 zero = {0.f, 0.f, 0.f, 0.f};
  f32x4 acc[2][2];
#pragma unroll
  for (int i = 0; i < 2; ++i)
#pragma unroll
    for (int j = 0; j < 2; ++j) acc[i][j] = zero;

  // staging chunks: c = p*256 + t; trow = c>>3, slot = c&7, src col-group slot^(trow&7)
  const int trow0 = t >> 3, slot0 = t & 7;           // p=0
  const int scg0 = (slot0 ^ (trow0 & 7)) * 8;
  const int arow0 = (m0 + trow0 > 4111) ? 4111 : m0 + trow0;
  const int trow1 = trow0 + 32, slot1 = slot0;       // p=1 (c = 256+t)
  const int scg1 = (slot1 ^ (trow1 & 7)) * 8;
  const int arow1 = (m0 + trow1 > 4111) ? 4111 : m0 + trow1;
  // read slots (XOR by row&7 = lr&7)
  const int rs0 = ((0 * 4 + lg) ^ (lr & 7)) * 8;     // kf=0
  const int rs1 = ((1 * 4 + lg) ^ (lr & 7)) * 8;     // kf=1

  for (int kt = 0; kt < 16; ++kt) {
    const int k0 = kt * 64;
    gload16(A + (size_t)arow0 * 1024 + k0 + scg0, &As[(t & ~63) * 8]);
    gload16(A + (size_t)arow1 * 1024 + k0 + scg1, &As[2048 + (t & ~63) * 8]);
    gload16(Bw + (size_t)(n0 + trow0) * 1024 + k0 + scg0, &Bs[(t & ~63) * 8]);
    gload16(Bw + (size_t)(n0 + trow1) * 1024 + k0 + scg1, &Bs[2048 + (t & ~63) * 8]);
    __syncthreads();   // drains vmcnt(0): staged data visible
    bf16x8 af[2][2], bfr[2][2];
#pragma unroll
    for (int i = 0; i < 2; ++i) {
      int ra = wm * 32 + i * 16 + lr;
      int rb = wn * 32 + i * 16 + lr;
      af[i][0]  = *(const bf16x8*)&As[ra * 64 + rs0];
      af[i][1]  = *(const bf16x8*)&As[ra * 64 + rs1];
      bfr[i][0] = *(const bf16x8*)&Bs[rb * 64 + rs0];
      bfr[i][1] = *(const bf16x8*)&Bs[rb * 64 + rs1];
    }
#pragma unroll
    for (int i = 0; i < 2; ++i)
#pragma unroll
      for (int j = 0; j < 2; ++j) {
        acc[i][j] = __builtin_amdgcn_mfma_f32_16x16x32_bf16(af[i][0], bfr[j][0], acc[i][j], 0, 0, 0);
        acc[i][j] = __builtin_amdgcn_mfma_f32_16x16x32_bf16(af[i][1], bfr[j][1], acc[i][j], 0, 0, 0);
      }
    __syncthreads();   // all reads done before next stage overwrites
  }

  // epilogue: residual (gathered hidden) + bias
#pragma unroll
  for (int i = 0; i < 2; ++i)
#pragma unroll
    for (int j = 0; j < 2; ++j)
#pragma unroll
      for (int reg = 0; reg < 4; ++reg) {
        int row = m0 + wm * 32 + i * 16 + lg * 4 + reg;
        int col = n0 + wn * 32 + j * 16 + lr;
        if (row < 4112) {
          int g = gidx[row];
          out[(size_t)row * 1024 + col] =
              tbl_row(0, g, lhs, rhs)[col] + bo[col] + acc[i][j][reg];
        }
      }
}

extern "C" void kernel_launch(void* const* d_in, const int* in_sizes, int n_in,
                              void* d_out, int out_size, void* d_ws, size_t ws_size,
                              hipStream_t stream) {
  const int*   gidx = (const int*)d_in[0];
  const float* lhs  = (const float*)d_in[1];
  const float* rhs  = (const float*)d_in[2];
  const float* Wo   = (const float*)d_in[3];
  const float* bo   = (const float*)d_in[4];
  float* out = (float*)d_out;

  u16* q_bf    = (u16*)d_ws;                      // 4112*1024 bf16 = 8.42 MB each
  u16* k_bf    = q_bf + (size_t)NR * 1024;
  u16* v_bf    = k_bf + (size_t)NR * 1024;
  u16* attn_ws = v_bf + (size_t)NR * 1024;
  u16* wo_bf   = attn_ws + (size_t)NR * 1024;     // 1024*1024 bf16 = 2.10 MB

  gather_cvt_kernel<<<3 * NR + 1024, 256, 0, stream>>>(gidx, lhs, rhs, Wo,
                                                       q_bf, k_bf, v_bf, wo_bf);
  attn_kernel<<<512, 512, 0, stream>>>(q_bf, k_bf, v_bf, attn_ws);
  gemm_kernel<<<1040, 256, 0, stream>>>(attn_ws, wo_bf, bo, gidx, lhs, rhs, out);
}

// Round 9
// 286.986 us; speedup vs baseline: 1.1023x; 1.0143x over previous
//
#include <hip/hip_runtime.h>
#include <hip/hip_bf16.h>

typedef __attribute__((ext_vector_type(8))) short bf16x8;
typedef __attribute__((ext_vector_type(4))) float f32x4;
typedef unsigned short u16;
typedef unsigned int u32;

#define LHS_STRIDE 8421376   // 16*514*1024 floats per stack slot
#define RHS_STRIDE 524288    // 512*1024 floats per stack slot
#define TBL_SPLIT  8224      // 16*514
#define AN 257               // sequence length
#define NR 4112              // 16*257 total rows
#define KSD 72               // K LDS row stride: 144B (16B-mult, bank stride 4 -> even spread)
#define VSD 260              // V^T LDS row stride

// row pointer into the concatenated [lhs | rhs] table for stack slot s
__device__ __forceinline__ const float* tbl_row(int s, int g,
    const float* __restrict__ lhs, const float* __restrict__ rhs) {
  if (g < TBL_SPLIT) return lhs + (size_t)s * LHS_STRIDE + (size_t)g * 1024;
  return rhs + (size_t)s * RHS_STRIDE + (size_t)(g - TBL_SPLIT) * 1024;
}

__device__ __forceinline__ u16 f2b(float x) {
  union { __hip_bfloat16 b; u16 u; } c;
  c.b = __float2bfloat16(x);
  return c.u;
}

__device__ __forceinline__ u32 pk2(float a, float b) {
  return (u32)f2b(a) | ((u32)f2b(b) << 16);
}

__device__ __forceinline__ bf16x8 mk8(ushort4 a, ushort4 b) {
  bf16x8 r;
  r[0] = (short)a.x; r[1] = (short)a.y; r[2] = (short)a.z; r[3] = (short)a.w;
  r[4] = (short)b.x; r[5] = (short)b.y; r[6] = (short)b.z; r[7] = (short)b.w;
  return r;
}

// async global->LDS, 16B per lane; LDS dest = wave-uniform base + lane*16
__device__ __forceinline__ void gload16(const u16* g, u16* l) {
  __builtin_amdgcn_global_load_lds((const __attribute__((address_space(1))) void*)g,
                                   (__attribute__((address_space(3))) void*)l,
                                   16, 0, 0);
}

// ---------------------------------------------------------------------------
// gather_cvt: blocks 0..4111 -> q (scaled 1/8), 4112..8223 -> k, 8224..12335 -> v,
// 12336..13359 -> Wo rows. One 4KB row per block, coalesced, f32 -> bf16.
__global__ void gather_cvt_kernel(
    const int* __restrict__ gidx, const float* __restrict__ lhs,
    const float* __restrict__ rhs, const float* __restrict__ Wo,
    u16* __restrict__ q_bf, u16* __restrict__ k_bf, u16* __restrict__ v_bf,
    u16* __restrict__ wo_bf) {
  const int blk = blockIdx.x, t = threadIdx.x;
  const float* src;
  u16* dst;
  float sc = 1.0f;
  if (blk < 3 * NR) {
    const int s = blk / NR + 1;            // 1=q, 2=k, 3=v
    const int row = blk - (s - 1) * NR;
    src = tbl_row(s, gidx[row], lhs, rhs);
    if (s == 1) { sc = 0.125f; dst = q_bf + (size_t)row * 1024; }
    else if (s == 2) dst = k_bf + (size_t)row * 1024;
    else dst = v_bf + (size_t)row * 1024;
  } else {
    const int row = blk - 3 * NR;          // 0..1023
    src = Wo + (size_t)row * 1024;
    dst = wo_bf + (size_t)row * 1024;
  }
  float4 v = *(const float4*)(src + t * 4);
  *(ushort4*)(dst + t * 4) =
      make_ushort4(f2b(sc * v.x), f2b(sc * v.y), f2b(sc * v.z), f2b(sc * v.w));
}

// ---------------------------------------------------------------------------
// attn: one block per (b,h,half), 8 waves; half 0 owns q-tiles {wave, 16},
// half 1 owns {wave+8}. Swapped QK^T (scores lane-local for q=lr), deferred-
// normalization softmax (unnormalized bf16 P; output scaled at store by the
// CORRECT row's inv, fetched via shfl since the PV output row is lg*4+reg).
struct __align__(16) AttnSmem {
  u16 K[272 * KSD];   // 39168 B; rows 257..271 stale (scores masked post-MFMA)
  u16 VT[64 * VSD];   // 33280 B; keys 0..256 written, 257..259 never read
};                    // 72448 B -> exactly 2 blocks/CU

__global__ __launch_bounds__(512) void attn_kernel(
    const u16* __restrict__ q_bf, const u16* __restrict__ k_bf,
    const u16* __restrict__ v_bf, u16* __restrict__ attn_out) {
  __shared__ AttnSmem sm;
  const int bh = blockIdx.x >> 1, half = blockIdx.x & 1;
  const int b = bh >> 4, h = bh & 15;
  const int t = threadIdx.x, wave = t >> 6, lane = t & 63;
  const int lg = lane >> 4, lr = lane & 15;
  const u16* qb = q_bf + (size_t)b * AN * 1024 + h * 64;
  const u16* kb = k_bf + (size_t)b * AN * 1024 + h * 64;
  const u16* vb = v_bf + (size_t)b * AN * 1024 + h * 64;

  // ---- stage K row-major (16B chunks) and V^T (reg transpose, scalar writes)
  {
    const int r8 = t >> 3, c8 = (t & 7) * 8;
#pragma unroll
    for (int p = 0; p < 5; ++p) {
      int r = p * 64 + r8;
      if (r < AN) {
        uint4 kx = *(const uint4*)(kb + (size_t)r * 1024 + c8);
        *(uint4*)&sm.K[r * KSD + c8] = kx;
        ushort4 v0 = *(const ushort4*)(vb + (size_t)r * 1024 + c8);
        ushort4 v1 = *(const ushort4*)(vb + (size_t)r * 1024 + c8 + 4);
        sm.VT[(c8 + 0) * VSD + r] = v0.x; sm.VT[(c8 + 1) * VSD + r] = v0.y;
        sm.VT[(c8 + 2) * VSD + r] = v0.z; sm.VT[(c8 + 3) * VSD + r] = v0.w;
        sm.VT[(c8 + 4) * VSD + r] = v1.x; sm.VT[(c8 + 5) * VSD + r] = v1.y;
        sm.VT[(c8 + 6) * VSD + r] = v1.z; sm.VT[(c8 + 7) * VSD + r] = v1.w;
      }
    }
  }

  // ---- Q fragments for owned row-tiles: direct 16B bf16 loads (pre-scaled)
  int rts[2];
  int ntile;
  if (half == 0) { rts[0] = wave; rts[1] = 16; ntile = (wave == 0) ? 2 : 1; }
  else           { rts[0] = wave + 8; rts[1] = 0; ntile = 1; }
  bf16x8 qa[2][2];
#pragma unroll
  for (int ti = 0; ti < 2; ++ti) {
    if (ti < ntile) {
      int qrow = rts[ti] * 16 + lr; if (qrow > 256) qrow = 256;
      const u16* qp = qb + (size_t)qrow * 1024 + lg * 8;
      qa[ti][0] = *(const bf16x8*)qp;
      qa[ti][1] = *(const bf16x8*)(qp + 32);
    }
  }
  __syncthreads();   // the only barrier

  const int srcE = lr + ((lane & 16) << 1);  // lr + 32*(lg&1)
  const int srcO = srcE + 16;
  const bool useE = (lg < 2);

  for (int ti = 0; ti < ntile; ++ti) {
    const int r0 = rts[ti] * 16;

    // ---- QK^T swapped: lane holds S[q=lr][k=nf*16+lg*4+reg]
    f32x4 s[17];
#pragma unroll
    for (int nf = 0; nf < 17; ++nf) {
      const u16* kp = &sm.K[(nf * 16 + lr) * KSD + lg * 8];
      ushort4 x0 = *(const ushort4*)kp;
      ushort4 x1 = *(const ushort4*)(kp + 4);
      ushort4 y0 = *(const ushort4*)(kp + 32);
      ushort4 y1 = *(const ushort4*)(kp + 36);
      f32x4 acc = {0.f, 0.f, 0.f, 0.f};
      acc = __builtin_amdgcn_mfma_f32_16x16x32_bf16(mk8(x0, x1), qa[ti][0], acc, 0, 0, 0);
      acc = __builtin_amdgcn_mfma_f32_16x16x32_bf16(mk8(y0, y1), qa[ti][1], acc, 0, 0, 0);
      s[nf] = acc;
    }
    // mask keys >= 257 (nf=16 holds keys 256+lg*4+reg; only (lg=0,reg=0) real)
    s[16][1] = -1e30f; s[16][2] = -1e30f; s[16][3] = -1e30f;
    if (lg != 0) s[16][0] = -1e30f;

    // ---- softmax max: in-lane over 68 values + reduce across 4 lanes sharing lr
    float m = -1e30f;
#pragma unroll
    for (int nf = 0; nf < 17; ++nf)
      m = fmaxf(m, fmaxf(fmaxf(s[nf][0], s[nf][1]), fmaxf(s[nf][2], s[nf][3])));
    m = fmaxf(m, __shfl_xor(m, 16));
    m = fmaxf(m, __shfl_xor(m, 32));

    // ---- exp + pack UNNORMALIZED w into bf16 pairs (s dies as p fills: peak<128 VGPR)
    u32 p[34];
    float sum = 0.f;
#pragma unroll
    for (int nf = 0; nf < 17; ++nf) {
      float w0 = __expf(s[nf][0] - m), w1 = __expf(s[nf][1] - m);
      float w2 = __expf(s[nf][2] - m), w3 = __expf(s[nf][3] - m);
      sum += (w0 + w1) + (w2 + w3);
      p[2 * nf]     = pk2(w0, w1);
      p[2 * nf + 1] = pk2(w2, w3);
    }
    sum += __shfl_xor(sum, 16);
    sum += __shfl_xor(sum, 32);
    const float inv = 1.0f / sum;   // normalizer for q-row = lr (this lane's score row)

    // PV output row is q = lg*4+reg (C/D layout), NOT lr: fetch that row's inv.
    // Source lane lg*4+reg < 16 has lr == lg*4+reg and holds the reduced sum.
    float invq[4];
#pragma unroll
    for (int reg = 0; reg < 4; ++reg)
      invq[reg] = __shfl(inv, lg * 4 + reg);

    // ---- P x V with in-register P redistribution (no LDS round-trip)
    f32x4 zero = {0.f, 0.f, 0.f, 0.f};
    f32x4 o[4] = {zero, zero, zero, zero};
#pragma unroll
    for (int ks = 0; ks < 8; ++ks) {
      u32 A0 = (u32)__shfl((int)p[4 * ks], srcE),     A1 = (u32)__shfl((int)p[4 * ks + 1], srcE);
      u32 A2 = (u32)__shfl((int)p[4 * ks], srcO),     A3 = (u32)__shfl((int)p[4 * ks + 1], srcO);
      u32 B0 = (u32)__shfl((int)p[4 * ks + 2], srcE), B1 = (u32)__shfl((int)p[4 * ks + 3], srcE);
      u32 B2 = (u32)__shfl((int)p[4 * ks + 2], srcO), B3 = (u32)__shfl((int)p[4 * ks + 3], srcO);
      union { u32 w[4]; bf16x8 v; } pa;
      pa.w[0] = useE ? A0 : B0; pa.w[1] = useE ? A1 : B1;
      pa.w[2] = useE ? A2 : B2; pa.w[3] = useE ? A3 : B3;
#pragma unroll
      for (int nd = 0; nd < 4; ++nd) {
        const u16* vp = &sm.VT[(nd * 16 + lr) * VSD + ks * 32 + lg * 8];
        bf16x8 vbr = mk8(*(const ushort4*)vp, *(const ushort4*)(vp + 4));
        o[nd] = __builtin_amdgcn_mfma_f32_16x16x32_bf16(pa.v, vbr, o[nd], 0, 0, 0);
      }
    }
    {  // ks=8: only key 256 real; masked exps are exactly 0 so pa needs no guard
      union { u32 w[4]; bf16x8 v; } pa;
      pa.w[0] = p[32] & 0xFFFFu;   // low half = w for key 256 (0 unless lg==0,reg==0)
      pa.w[1] = 0; pa.w[2] = 0; pa.w[3] = 0;
#pragma unroll
      for (int nd = 0; nd < 4; ++nd) {
        union { u32 w[4]; bf16x8 v; } vv;
        vv.w[0] = (lg == 0) ? (u32)sm.VT[(nd * 16 + lr) * VSD + 256] : 0u;
        vv.w[1] = 0; vv.w[2] = 0; vv.w[3] = 0;
        o[nd] = __builtin_amdgcn_mfma_f32_16x16x32_bf16(pa.v, vv.v, o[nd], 0, 0, 0);
      }
    }

    // ---- store with deferred normalization: row = q = lg*4+reg, col = nd*16+lr
#pragma unroll
    for (int nd = 0; nd < 4; ++nd)
#pragma unroll
      for (int reg = 0; reg < 4; ++reg) {
        int row = r0 + lg * 4 + reg;
        if (row < AN)
          attn_out[(size_t)(b * AN + row) * 1024 + h * 64 + nd * 16 + lr] =
              f2b(o[nd][reg] * invq[reg]);
      }
  }
}

// ---------------------------------------------------------------------------
// out[4112][1024] = attn(bf16) x Wo(bf16)^T + bo + hidden(gathered), f32 out.
// 64x64x64 tiles, single-buffered gload_lds, 1040 blocks (~4/CU -> 4 waves/SIMD).
// Row layout: 8 x 16B slots; slot stored/read XOR (row&7) -> conflict-free b128.
__global__ __launch_bounds__(256) void gemm_kernel(
    const u16* __restrict__ A, const u16* __restrict__ Bw,
    const float* __restrict__ bo, const int* __restrict__ gidx,
    const float* __restrict__ lhs, const float* __restrict__ rhs,
    float* __restrict__ out) {
  __shared__ __align__(16) u16 As[64 * 64];
  __shared__ __align__(16) u16 Bs[64 * 64];
  const int t = threadIdx.x, wave = t >> 6, lane = t & 63;
  const int lg = lane >> 4, lr = lane & 15;
  // XCD swizzle: 1040 = 8 x 130; same-XCD blocks get consecutive linear ids
  const int linear = (blockIdx.x & 7) * 130 + (blockIdx.x >> 3);
  const int mt = linear >> 4, nt = linear & 15;     // 65 x 16 tiles
  const int m0 = mt * 64, n0 = nt * 64;
  const int wm = wave >> 1, wn = wave & 1;

  f32x4 zero = {0.f, 0.f, 0.f, 0.f};
  f32x4 acc[2][2];
#pragma unroll
  for (int i = 0; i < 2; ++i)
#pragma unroll
    for (int j = 0; j < 2; ++j) acc[i][j] = zero;

  // staging chunks: c = p*256 + t; trow = c>>3, slot = c&7, src col-group slot^(trow&7)
  const int trow0 = t >> 3, slot0 = t & 7;           // p=0
  const int scg0 = (slot0 ^ (trow0 & 7)) * 8;
  const int arow0 = (m0 + trow0 > 4111) ? 4111 : m0 + trow0;
  const int trow1 = trow0 + 32, slot1 = slot0;       // p=1 (c = 256+t)
  const int scg1 = (slot1 ^ (trow1 & 7)) * 8;
  const int arow1 = (m0 + trow1 > 4111) ? 4111 : m0 + trow1;
  // read slots (XOR by row&7 = lr&7)
  const int rs0 = ((0 * 4 + lg) ^ (lr & 7)) * 8;     // kf=0
  const int rs1 = ((1 * 4 + lg) ^ (lr & 7)) * 8;     // kf=1

  for (int kt = 0; kt < 16; ++kt) {
    const int k0 = kt * 64;
    gload16(A + (size_t)arow0 * 1024 + k0 + scg0, &As[(t & ~63) * 8]);
    gload16(A + (size_t)arow1 * 1024 + k0 + scg1, &As[2048 + (t & ~63) * 8]);
    gload16(Bw + (size_t)(n0 + trow0) * 1024 + k0 + scg0, &Bs[(t & ~63) * 8]);
    gload16(Bw + (size_t)(n0 + trow1) * 1024 + k0 + scg1, &Bs[2048 + (t & ~63) * 8]);
    __syncthreads();   // drains vmcnt(0): staged data visible
    bf16x8 af[2][2], bfr[2][2];
#pragma unroll
    for (int i = 0; i < 2; ++i) {
      int ra = wm * 32 + i * 16 + lr;
      int rb = wn * 32 + i * 16 + lr;
      af[i][0]  = *(const bf16x8*)&As[ra * 64 + rs0];
      af[i][1]  = *(const bf16x8*)&As[ra * 64 + rs1];
      bfr[i][0] = *(const bf16x8*)&Bs[rb * 64 + rs0];
      bfr[i][1] = *(const bf16x8*)&Bs[rb * 64 + rs1];
    }
#pragma unroll
    for (int i = 0; i < 2; ++i)
#pragma unroll
      for (int j = 0; j < 2; ++j) {
        acc[i][j] = __builtin_amdgcn_mfma_f32_16x16x32_bf16(af[i][0], bfr[j][0], acc[i][j], 0, 0, 0);
        acc[i][j] = __builtin_amdgcn_mfma_f32_16x16x32_bf16(af[i][1], bfr[j][1], acc[i][j], 0, 0, 0);
      }
    __syncthreads();   // all reads done before next stage overwrites
  }

  // epilogue: residual (gathered hidden) + bias
#pragma unroll
  for (int i = 0; i < 2; ++i)
#pragma unroll
    for (int j = 0; j < 2; ++j)
#pragma unroll
      for (int reg = 0; reg < 4; ++reg) {
        int row = m0 + wm * 32 + i * 16 + lg * 4 + reg;
        int col = n0 + wn * 32 + j * 16 + lr;
        if (row < 4112) {
          int g = gidx[row];
          out[(size_t)row * 1024 + col] =
              tbl_row(0, g, lhs, rhs)[col] + bo[col] + acc[i][j][reg];
        }
      }
}

extern "C" void kernel_launch(void* const* d_in, const int* in_sizes, int n_in,
                              void* d_out, int out_size, void* d_ws, size_t ws_size,
                              hipStream_t stream) {
  const int*   gidx = (const int*)d_in[0];
  const float* lhs  = (const float*)d_in[1];
  const float* rhs  = (const float*)d_in[2];
  const float* Wo   = (const float*)d_in[3];
  const float* bo   = (const float*)d_in[4];
  float* out = (float*)d_out;

  u16* q_bf    = (u16*)d_ws;                      // 4112*1024 bf16 = 8.42 MB each
  u16* k_bf    = q_bf + (size_t)NR * 1024;
  u16* v_bf    = k_bf + (size_t)NR * 1024;
  u16* attn_ws = v_bf + (size_t)NR * 1024;
  u16* wo_bf   = attn_ws + (size_t)NR * 1024;     // 1024*1024 bf16 = 2.10 MB

  gather_cvt_kernel<<<3 * NR + 1024, 256, 0, stream>>>(gidx, lhs, rhs, Wo,
                                                       q_bf, k_bf, v_bf, wo_bf);
  attn_kernel<<<512, 512, 0, stream>>>(q_bf, k_bf, v_bf, attn_ws);
  gemm_kernel<<<1040, 256, 0, stream>>>(attn_ws, wo_bf, bo, gidx, lhs, rhs, out);
}